// Round 5
// baseline (503.879 us; speedup 1.0000x reference)
//
#include <hip/hip_runtime.h>

// Problem constants: B=4, C=64, N=512*512, K=400
constexpr int BB   = 4;
constexpr int CC   = 64;
constexpr int NPIX = 512 * 512;      // 262144
constexpr int KK   = 400;

// ---------------- accum config ----------------
constexpr int PPB  = 4096;           // pixels per block
constexpr int TPX  = 128;            // pixels per LDS feature tile
constexpr int NTL  = PPB / TPX;      // 32 tiles
constexpr int TROW = 68;             // tile row stride (floats), [p][c] layout, 16B-aligned rows
constexpr int ATH  = 1024;           // 16 waves
constexpr int NW   = 16;             // owner classes (k & 15), one per wave

// ---------------------------------------------------------------------------
// Stage 1: per-block [K x 64ch] histogram; DS traffic reduced 4x vs prev:
//   - tile stored PIXEL-major [p][c] (stride 68) -> one wave-instr covers
//     4 pixels: lanes = 4 pixel-slots (q=lane>>4) x 16 channel-quads (g).
//     Per 4-px group: 1 list b32 (quarter-broadcast) + 1 tile ds_read_b128 +
//     1 sums b128 read + 1 sums b128 write  == 1 DS instr per pixel.
//   - duplicate cells within a group (~1.5%, wave-uniform detect via
//     readlane x4 + 6 compares) -> serial b32 slow path (correct ordering).
//   - staging: 8 waves do a register 4x4 transpose (4 x float4 global loads,
//     4 x ds_write_b128) -> 32 wide writes per tile vs 128 narrow.
//   - wave w owns cells with (k & 15) == w  -> plain LDS RMW race-free.
// grid = B * 64 chunks = 256 blocks (1 per CU), 1024 threads
// ---------------------------------------------------------------------------
__global__ __launch_bounds__(ATH) void accum_kernel(
    const float* __restrict__ feat,   // [B, C, N]
    const int*   __restrict__ idx,    // [B, N]
    float* __restrict__ g_sums,       // [B, K, C]
    float* __restrict__ g_cnt)        // [B, K]
{
    __shared__ float    s_sums[KK * CC];       // 102400 B, [k][64] (b128 rows)
    __shared__ float    s_cnt[KK];             //   1600 B
    __shared__ unsigned s_list[PPB];           //  16384 B: (pix<<16) | (k<<6)
    __shared__ float    s_tile[TPX * TROW];    //  34816 B, [p][c] stride 68
    __shared__ int      s_wcnt[NW];

    const int t     = threadIdx.x;
    const int lane  = t & 63;
    const int w     = t >> 6;                  // wave id 0..15 == owner class
    const int b     = blockIdx.x >> 6;
    const int chunk = blockIdx.x & 63;
    const int p0    = chunk * PPB;

    // zero LDS
    for (int e = t; e < KK * CC; e += ATH) s_sums[e] = 0.0f;
    for (int e = t; e < KK; e += ATH) s_cnt[e] = 0.0f;
    __syncthreads();

    const int* idx_b = idx + b * NPIX + p0;
    const unsigned long long lmask = (1ull << lane) - 1ull;

    // ---- pass 1: per-wave ownership count; cell counts spread across waves ----
    int myCnt = 0;
    for (int j = 0; j < 64; ++j) {
        int k = idx_b[j * 64 + lane];
        if ((j >> 2) == w) atomicAdd(&s_cnt[k], 1.0f);
        myCnt += __popcll(__ballot((k & 15) == w));
    }
    if (lane == 0) s_wcnt[w] = myCnt;
    __syncthreads();

    int base = 0;
#pragma unroll
    for (int j = 0; j < NW; ++j) { int cj = s_wcnt[j]; base += (j < w) ? cj : 0; }

    // ---- pass 2: compact owned pixels (sorted by pixel), save prefix/lane ----
    int pos = base;
    int sp = 0, se = 0;   // lane j holds pos before/after pass-iteration j
    for (int j = 0; j < 64; ++j) {
        int i = j * 64 + lane;
        int k = idx_b[i];
        bool own = ((k & 15) == w);
        unsigned long long m = __ballot(own);
        if (lane == j) sp = pos;
        if (own) s_list[pos + __popcll(m & lmask)] =
                     ((unsigned)i << 16) | ((unsigned)k << 6);
        pos += __popcll(m);
        if (lane == j) se = pos;
    }
    // own-segment reads need no barrier (per-wave DS ordering)

    // ---- staging setup (waves 0..7 only): 4x4 register transpose ----
    const bool stager = (w < 8);
    const int  sgq  = t & 15;                 // pixel-quad in 64-px segment
    const int  scrq = (t >> 4) & 15;          // channel quad 0..15
    const int  sseg = (t >> 8) & 1;           // 64-px segment 0..1
    const int  spx  = sseg * 64 + sgq * 4;    // pixel offset within tile 0..127
    const float* fbase = feat + ((size_t)b * CC + (size_t)(scrq * 4)) * NPIX + p0 + spx;

    float4 c0, c1, c2, c3;
    if (stager) {
        c0 = *(const float4*)(fbase + 0 * (size_t)NPIX);
        c1 = *(const float4*)(fbase + 1 * (size_t)NPIX);
        c2 = *(const float4*)(fbase + 2 * (size_t)NPIX);
        c3 = *(const float4*)(fbase + 3 * (size_t)NPIX);
    }

    const int q = lane >> 4;     // pixel slot 0..3
    const int g = lane & 15;     // channel quad 0..15

    for (int tl = 0; tl < NTL; ++tl) {
        __syncthreads();                       // prev tile fully consumed
        if (stager) {
            float* td = &s_tile[spx * TROW + scrq * 4];
            *(float4*)(td + 0 * TROW) = float4{c0.x, c1.x, c2.x, c3.x};
            *(float4*)(td + 1 * TROW) = float4{c0.y, c1.y, c2.y, c3.y};
            *(float4*)(td + 2 * TROW) = float4{c0.z, c1.z, c2.z, c3.z};
            *(float4*)(td + 3 * TROW) = float4{c0.w, c1.w, c2.w, c3.w};
        }
        __syncthreads();                       // tile staged
        if (stager && tl + 1 < NTL) {          // issue next loads under processing
            const float* fn = fbase + (tl + 1) * TPX;
            c0 = *(const float4*)(fn + 0 * (size_t)NPIX);
            c1 = *(const float4*)(fn + 1 * (size_t)NPIX);
            c2 = *(const float4*)(fn + 2 * (size_t)NPIX);
            c3 = *(const float4*)(fn + 3 * (size_t)NPIX);
        }

        int cur = __builtin_amdgcn_readlane(sp, 2 * tl);
        int end = __builtin_amdgcn_readlane(se, 2 * tl + 1);

        // 4 pixels per iteration: 4 DS instrs total (fast path)
        for (; cur + 4 <= end; cur += 4) {
            unsigned e = s_list[cur + q];              // broadcast per quarter
            int m = (int)(e & 0xFFFFu);                // k*64 (row base)
            int p = ((int)(e >> 16)) & (TPX - 1);

            int m0 = __builtin_amdgcn_readlane(m, 0);
            int m1 = __builtin_amdgcn_readlane(m, 16);
            int m2 = __builtin_amdgcn_readlane(m, 32);
            int m3 = __builtin_amdgcn_readlane(m, 48);
            bool dup = (m0 == m1) | (m0 == m2) | (m0 == m3) |
                       (m1 == m2) | (m1 == m3) | (m2 == m3);

            if (!dup) {
                float4 v = *(const float4*)&s_tile[p * TROW + 4 * g];
                float4 s = *(const float4*)&s_sums[m + 4 * g];
                s.x += v.x; s.y += v.y; s.z += v.z; s.w += v.w;
                *(float4*)&s_sums[m + 4 * g] = s;
            } else {
                // rare (~1.5%): serial per-pixel RMW, all 64 lanes = channels
                for (int qq = 0; qq < 4; ++qq) {
                    unsigned eq = s_list[cur + qq];    // broadcast
                    int mq = (int)(eq & 0xFFFFu);
                    int pq = ((int)(eq >> 16)) & (TPX - 1);
                    s_sums[mq + lane] += s_tile[pq * TROW + lane];
                }
            }
        }
        // tail (<4): serial per-pixel RMW
        for (; cur < end; ++cur) {
            unsigned e = s_list[cur];
            int m = (int)(e & 0xFFFFu);
            int p = ((int)(e >> 16)) & (TPX - 1);
            s_sums[m + lane] += s_tile[p * TROW + lane];
        }
    }
    __syncthreads();

    // ---- merge to global ----
    float* gs = g_sums + (size_t)b * KK * CC;
    for (int e = t; e < KK * CC; e += ATH) {
        float v = s_sums[e];
        if (v != 0.0f) atomicAdd(&gs[e], v);
    }
    float* gc = g_cnt + b * KK;
    for (int e = t; e < KK; e += ATH) {
        float v = s_cnt[e];
        if (v != 0.0f) atomicAdd(&gc[e], v);
    }
}

// ---------------- gather config (unchanged from R4 — control) ----------------
constexpr int GTH  = 1024;               // 16 waves
constexpr int GPIX = 4096;               // pixels per block
constexpr int MST  = 65;                 // float stride: read bank = (k+c)%32

__global__ __launch_bounds__(GTH) void gather_kernel(
    const float* __restrict__ g_sums, // [B, K, C]
    const float* __restrict__ g_cnt,  // [B, K]
    const int*   __restrict__ idx,    // [B, N]
    float* __restrict__ out)          // [B, C, N]
{
    __shared__ float s_mean[KK * MST];       // 104000 B -> 1 block/CU

    const int t    = threadIdx.x;
    const int lane = t & 63;
    const int w    = t >> 6;
    const int b    = blockIdx.x >> 6;
    const int p0   = (blockIdx.x & 63) * GPIX;

    // hoist this lane's 4 pixel indices to registers (coalesced int4, once)
    int4 kk = ((const int4*)(idx + b * NPIX + p0 + w * 256))[lane];
    const int ax = kk.x * MST, ay = kk.y * MST, az = kk.z * MST, aw2 = kk.w * MST;

    // stage means (divide fused)
    const float4* ms = (const float4*)(g_sums + (size_t)b * KK * CC);
    const float*  cb = g_cnt + b * KK;
    for (int e = t; e < KK * (CC / 4); e += GTH) {
        int k = e >> 4;
        float4 v = ms[e];
        float inv = 1.0f / fmaxf(cb[k], 1.0f);
        float* dst = &s_mean[k * MST + (e & 15) * 4];
        dst[0] = v.x * inv; dst[1] = v.y * inv;
        dst[2] = v.z * inv; dst[3] = v.w * inv;
    }
    __syncthreads();

    // channel sweep: block writes one contiguous 16 KB segment per step
    float* ob = out + (size_t)b * CC * NPIX + p0 + w * 256 + lane * 4;
    const int csk = (blockIdx.x * 7) & 63;   // decorrelate rows across blocks

    for (int s = 0; s < CC; ++s) {
        const int c = (s + csk) & 63;
        float4 v;
        v.x = s_mean[ax + c];
        v.y = s_mean[ay + c];
        v.z = s_mean[az + c];
        v.w = s_mean[aw2 + c];
        *(float4*)(ob + (size_t)c * NPIX) = v;
    }
}

extern "C" void kernel_launch(void* const* d_in, const int* in_sizes, int n_in,
                              void* d_out, int out_size, void* d_ws, size_t ws_size,
                              hipStream_t stream) {
    const float* feat = (const float*)d_in[0];   // [B, C, N] fp32
    const int*   idx  = (const int*)d_in[1];     // [B, N] int32
    float* out    = (float*)d_out;               // [B, C, N] fp32
    float* g_sums = (float*)d_ws;                // B*K*C floats = 409600 B
    float* g_cnt  = g_sums + BB * KK * CC;       // B*K floats   =   6400 B

    hipMemsetAsync(d_ws, 0, (size_t)(BB * KK * CC + BB * KK) * sizeof(float), stream);

    accum_kernel<<<BB * 64, ATH, 0, stream>>>(feat, idx, g_sums, g_cnt);
    gather_kernel<<<BB * 64, GTH, 0, stream>>>(g_sums, g_cnt, idx, out);
}